// Round 1
// baseline (3499.794 us; speedup 1.0000x reference)
//
#include <hip/hip_runtime.h>
#include <math.h>

#define D_MODEL 2048
#define T_SEQ   2048
#define BATCH   2
#define NHEADS  16
#define HDIM    128
#define MROWS   (BATCH*T_SEQ)   // 4096
#define CLIPV   8.0f
#define NEGBIG  (-1e30f)

// ---------------------------------------------------------------------------
// GEMM  C = A * B^T (+bias).  A: MxK row-major, Bm: NxK row-major (einsum
// 'btd,ed->bte' is exactly this NT layout -> both operands K-contiguous).
// MODE 0: QKV epilogue: +bias, clip to +-8, scatter into Q/K/V (B,H,T,HDIM).
// MODE 1: plain epilogue: +bias, row-major C.
// Tile 64x64, BK=32, 256 threads (16x16), 4x4 per thread, fp32 VALU.
// ---------------------------------------------------------------------------
template<int MODE>
__global__ __launch_bounds__(256)
void gemm_nt(const float* __restrict__ A, const float* __restrict__ Bm,
             const float* __restrict__ bias, float* __restrict__ C,
             float* __restrict__ Qb, float* __restrict__ Kb, float* __restrict__ Vb,
             int M, int N, int K)
{
    // transposed tiles [k][m], pad 64->68 (keeps rows 16B aligned, breaks bank stride)
    __shared__ float As[32][68];
    __shared__ float Bs[32][68];

    const int tid  = threadIdx.x;
    const int tx   = tid & 15;
    const int ty   = tid >> 4;
    const int row0 = blockIdx.y * 64;
    const int col0 = blockIdx.x * 64;

    float acc[4][4];
    #pragma unroll
    for (int i = 0; i < 4; ++i)
        #pragma unroll
        for (int j = 0; j < 4; ++j) acc[i][j] = 0.f;

    const int r_a = tid >> 3;          // 0..31
    const int k4  = (tid & 7) << 2;    // 0,4,...,28

    for (int kt = 0; kt < K; kt += 32) {
        #pragma unroll
        for (int l = 0; l < 2; ++l) {
            int r = r_a + l*32;
            float4 av = *(const float4*)&A[(size_t)(row0 + r)*K + kt + k4];
            As[k4+0][r] = av.x; As[k4+1][r] = av.y; As[k4+2][r] = av.z; As[k4+3][r] = av.w;
            float4 bv = *(const float4*)&Bm[(size_t)(col0 + r)*K + kt + k4];
            Bs[k4+0][r] = bv.x; Bs[k4+1][r] = bv.y; Bs[k4+2][r] = bv.z; Bs[k4+3][r] = bv.w;
        }
        __syncthreads();
        #pragma unroll
        for (int kk = 0; kk < 32; ++kk) {
            float4 a = *(const float4*)&As[kk][ty*4];
            float4 b = *(const float4*)&Bs[kk][tx*4];
            float ar[4] = {a.x, a.y, a.z, a.w};
            float br[4] = {b.x, b.y, b.z, b.w};
            #pragma unroll
            for (int i = 0; i < 4; ++i)
                #pragma unroll
                for (int j = 0; j < 4; ++j)
                    acc[i][j] = fmaf(ar[i], br[j], acc[i][j]);
        }
        __syncthreads();
    }

    if (MODE == 1) {
        const int n0 = col0 + tx*4;
        #pragma unroll
        for (int i = 0; i < 4; ++i) {
            int m = row0 + ty*4 + i;
            float4 o;
            o.x = acc[i][0] + bias[n0+0];
            o.y = acc[i][1] + bias[n0+1];
            o.z = acc[i][2] + bias[n0+2];
            o.w = acc[i][3] + bias[n0+3];
            *(float4*)&C[(size_t)m*N + n0] = o;
        }
    } else {
        // e = (s*16+h)*128 + d ; 64-col tiles never straddle a head boundary
        const int e0 = col0 + tx*4;
        const int s  = e0 >> 11;
        const int h  = (e0 >> 7) & 15;
        const int d0 = e0 & 127;
        float* dst = (s == 0) ? Qb : (s == 1) ? Kb : Vb;
        #pragma unroll
        for (int i = 0; i < 4; ++i) {
            int m = row0 + ty*4 + i;
            int b = m >> 11;          // T_SEQ = 2048
            int t = m & 2047;
            float4 o;
            o.x = fminf(fmaxf(acc[i][0] + bias[e0+0], -CLIPV), CLIPV);
            o.y = fminf(fmaxf(acc[i][1] + bias[e0+1], -CLIPV), CLIPV);
            o.z = fminf(fmaxf(acc[i][2] + bias[e0+2], -CLIPV), CLIPV);
            o.w = fminf(fmaxf(acc[i][3] + bias[e0+3], -CLIPV), CLIPV);
            *(float4*)&dst[(size_t)((b*NHEADS + h)*T_SEQ + t)*HDIM + d0] = o;
        }
    }
}

// ---------------------------------------------------------------------------
// RoPE in-place on Q and K, (B,H,T,HDIM) layout, host-provided sin/cos tables.
// pair (d, d+64): out[d] = f1*c - f2*s ; out[d+64] = f1*s + f2*c
// total threads = 2 * B*H * T * 64 = 2^23
// ---------------------------------------------------------------------------
__global__ __launch_bounds__(256)
void rope_kernel(float* __restrict__ Qb, float* __restrict__ Kb,
                 const float* __restrict__ sinT, const float* __restrict__ cosT)
{
    int idx = blockIdx.x * 256 + threadIdx.x;
    int d   = idx & 63;
    int t   = (idx >> 6) & (T_SEQ - 1);
    int bh  = (idx >> 17) & 31;
    float* buf = (idx >> 22) ? Kb : Qb;
    size_t base = ((size_t)bh * T_SEQ + t) * HDIM;
    float c  = cosT[t*64 + d];
    float s  = sinT[t*64 + d];
    float f1 = buf[base + d];
    float f2 = buf[base + 64 + d];
    buf[base + d]      = f1*c - f2*s;
    buf[base + 64 + d] = f1*s + f2*c;
}

// ---------------------------------------------------------------------------
// Causal flash attention, fp32. One block per (q-tile of 64, head, batch).
// 256 threads (16x16): scores S 64x64 as 4x4/thread, O 64x128 as 4x8/thread.
// Online softmax; row group = 16 consecutive lanes -> __shfl_xor reduce.
// ---------------------------------------------------------------------------
__global__ __launch_bounds__(256)
void attn_kernel(const float* __restrict__ Qb, const float* __restrict__ Kb,
                 const float* __restrict__ Vb, float* __restrict__ attout)
{
    __shared__ float Qt[128][68];   // transposed Q tile   [k][r]
    __shared__ float Kt[128][68];   // transposed K tile   [k][c]
    __shared__ float Vs[64][128];   // V tile row-major    [j][d]
    __shared__ float Ps[64][65];    // probabilities       [r][j]

    const int tid = threadIdx.x;
    const int tx  = tid & 15, ty = tid >> 4;
    const int qt  = blockIdx.x;
    const int h   = blockIdx.y;
    const int b   = blockIdx.z;
    const int bh  = b * NHEADS + h;
    const float* Qp = Qb + (size_t)bh * T_SEQ * HDIM + (size_t)qt * 64 * HDIM;
    const float* Kp = Kb + (size_t)bh * T_SEQ * HDIM;
    const float* Vp = Vb + (size_t)bh * T_SEQ * HDIM;

    #pragma unroll
    for (int l = 0; l < 8; ++l) {
        int idx = l*256 + tid;
        int r   = idx >> 5;
        int c4  = (idx & 31) << 2;
        float4 v = *(const float4*)&Qp[r*HDIM + c4];
        Qt[c4+0][r] = v.x; Qt[c4+1][r] = v.y; Qt[c4+2][r] = v.z; Qt[c4+3][r] = v.w;
    }

    float m_run[4], l_run[4], Oacc[4][8];
    #pragma unroll
    for (int i = 0; i < 4; ++i) {
        m_run[i] = NEGBIG; l_run[i] = 0.f;
        #pragma unroll
        for (int c = 0; c < 8; ++c) Oacc[i][c] = 0.f;
    }

    const float scale = 0.08838834764831843f;  // 1/sqrt(128)

    for (int kt = 0; kt <= qt; ++kt) {
        __syncthreads();
        #pragma unroll
        for (int l = 0; l < 8; ++l) {
            int idx = l*256 + tid;
            int r   = idx >> 5;
            int c4  = (idx & 31) << 2;
            float4 v = *(const float4*)&Kp[(size_t)(kt*64 + r)*HDIM + c4];
            Kt[c4+0][r] = v.x; Kt[c4+1][r] = v.y; Kt[c4+2][r] = v.z; Kt[c4+3][r] = v.w;
            float4 w = *(const float4*)&Vp[(size_t)(kt*64 + r)*HDIM + c4];
            *(float4*)&Vs[r][c4] = w;
        }
        __syncthreads();

        float S[4][4];
        #pragma unroll
        for (int i = 0; i < 4; ++i)
            #pragma unroll
            for (int j = 0; j < 4; ++j) S[i][j] = 0.f;

        #pragma unroll 8
        for (int k = 0; k < 128; ++k) {
            float4 a  = *(const float4*)&Qt[k][ty*4];
            float4 bb = *(const float4*)&Kt[k][tx*4];
            float ar[4] = {a.x, a.y, a.z, a.w};
            float br[4] = {bb.x, bb.y, bb.z, bb.w};
            #pragma unroll
            for (int i = 0; i < 4; ++i)
                #pragma unroll
                for (int j = 0; j < 4; ++j)
                    S[i][j] = fmaf(ar[i], br[j], S[i][j]);
        }

        const bool diag = (kt == qt);
        float alpha[4];
        #pragma unroll
        for (int i = 0; i < 4; ++i) {
            #pragma unroll
            for (int j = 0; j < 4; ++j) {
                S[i][j] *= scale;
                if (diag && (tx*4 + j > ty*4 + i)) S[i][j] = NEGBIG;
            }
            float mx = fmaxf(fmaxf(S[i][0], S[i][1]), fmaxf(S[i][2], S[i][3]));
            #pragma unroll
            for (int msk = 1; msk < 16; msk <<= 1)
                mx = fmaxf(mx, __shfl_xor(mx, msk, 64));
            float mnew = fmaxf(m_run[i], mx);
            alpha[i] = __expf(m_run[i] - mnew);
            float ps = 0.f;
            #pragma unroll
            for (int j = 0; j < 4; ++j) {
                float p = __expf(S[i][j] - mnew);
                Ps[ty*4+i][tx*4+j] = p;
                ps += p;
            }
            #pragma unroll
            for (int msk = 1; msk < 16; msk <<= 1)
                ps += __shfl_xor(ps, msk, 64);
            l_run[i] = l_run[i]*alpha[i] + ps;
            m_run[i] = mnew;
            #pragma unroll
            for (int c = 0; c < 8; ++c) Oacc[i][c] *= alpha[i];
        }
        __syncthreads();

        #pragma unroll 4
        for (int j = 0; j < 64; ++j) {
            float4 v0 = *(const float4*)&Vs[j][tx*8];
            float4 v1 = *(const float4*)&Vs[j][tx*8+4];
            #pragma unroll
            for (int i = 0; i < 4; ++i) {
                float p = Ps[ty*4+i][j];
                Oacc[i][0] = fmaf(p, v0.x, Oacc[i][0]);
                Oacc[i][1] = fmaf(p, v0.y, Oacc[i][1]);
                Oacc[i][2] = fmaf(p, v0.z, Oacc[i][2]);
                Oacc[i][3] = fmaf(p, v0.w, Oacc[i][3]);
                Oacc[i][4] = fmaf(p, v1.x, Oacc[i][4]);
                Oacc[i][5] = fmaf(p, v1.y, Oacc[i][5]);
                Oacc[i][6] = fmaf(p, v1.z, Oacc[i][6]);
                Oacc[i][7] = fmaf(p, v1.w, Oacc[i][7]);
            }
        }
    }

    // write att in (B,T,D_MODEL) layout for the out-projection GEMM
    #pragma unroll
    for (int i = 0; i < 4; ++i) {
        int t = qt*64 + ty*4 + i;
        float inv = 1.f / l_run[i];
        size_t o = ((size_t)(b*T_SEQ + t))*D_MODEL + h*HDIM + tx*8;
        float4 o0 = { Oacc[i][0]*inv, Oacc[i][1]*inv, Oacc[i][2]*inv, Oacc[i][3]*inv };
        float4 o1 = { Oacc[i][4]*inv, Oacc[i][5]*inv, Oacc[i][6]*inv, Oacc[i][7]*inv };
        *(float4*)&attout[o]     = o0;
        *(float4*)&attout[o + 4] = o1;
    }
}

// ---------------------------------------------------------------------------
extern "C" void kernel_launch(void* const* d_in, const int* in_sizes, int n_in,
                              void* d_out, int out_size, void* d_ws, size_t ws_size,
                              hipStream_t stream)
{
    const float* x     = (const float*)d_in[0];
    const float* w_qkv = (const float*)d_in[1];
    const float* b_qkv = (const float*)d_in[2];
    const float* w_out = (const float*)d_in[3];
    const float* b_out = (const float*)d_in[4];
    const float* psin  = (const float*)d_in[5];
    const float* pcos  = (const float*)d_in[6];
    float* out = (float*)d_out;

    const size_t per = (size_t)BATCH * NHEADS * T_SEQ * HDIM;  // 8,388,608 floats
    float* Qb = (float*)d_ws;
    float* Kb = Qb + per;
    float* Vb = Kb + per;
    float* Ab = Vb + per;   // attention output, (B,T,D) layout
    // total ws use: 4 * 33.55 MB = 134.2 MB

    // 1) QKV projection + bias + clip, scatter to (B,H,T,HDIM)
    gemm_nt<0><<<dim3(3*D_MODEL/64, MROWS/64), 256, 0, stream>>>(
        x, w_qkv, b_qkv, nullptr, Qb, Kb, Vb, MROWS, 3*D_MODEL, D_MODEL);
    // 2) RoPE on Q and K (tables from host)
    rope_kernel<<<(2u*BATCH*NHEADS*T_SEQ*64)/256, 256, 0, stream>>>(Qb, Kb, psin, pcos);
    // 3) causal flash attention
    attn_kernel<<<dim3(T_SEQ/64, NHEADS, BATCH), 256, 0, stream>>>(Qb, Kb, Vb, Ab);
    // 4) output projection + bias
    gemm_nt<1><<<dim3(D_MODEL/64, MROWS/64), 256, 0, stream>>>(
        Ab, w_out, b_out, out, nullptr, nullptr, nullptr, MROWS, D_MODEL, D_MODEL);
}

// Round 3
// 2144.546 us; speedup vs baseline: 1.6320x; 1.6320x over previous
//
#include <hip/hip_runtime.h>
#include <math.h>

#define D_MODEL 2048
#define T_SEQ   2048
#define BATCH   2
#define NHEADS  16
#define HDIM    128
#define MROWS   (BATCH*T_SEQ)   // 4096
#define CLIPV   8.0f
#define NEGBIG  (-1e30f)

typedef __attribute__((ext_vector_type(8))) short short8;   // 8 bf16 = 4 VGPR (MFMA A/B frag)
typedef __attribute__((ext_vector_type(4))) float f32x4;    // MFMA C/D frag

__device__ inline ushort f2bf(float f) {                    // fp32 -> bf16 RNE
    uint32_t u = __float_as_uint(f);
    return (ushort)((u + 0x7fffu + ((u >> 16) & 1u)) >> 16);
}

// ---------------------------------------------------------------------------
// fp32 -> bf16 convert, float4 in / ushort4 out
// ---------------------------------------------------------------------------
__global__ __launch_bounds__(256)
void cvt_bf16(const float* __restrict__ in, ushort* __restrict__ out, int n4)
{
    int i = blockIdx.x * 256 + threadIdx.x;
    if (i >= n4) return;
    float4 v = ((const float4*)in)[i];
    ushort4 o;
    o.x = f2bf(v.x); o.y = f2bf(v.y); o.z = f2bf(v.z); o.w = f2bf(v.w);
    ((ushort4*)out)[i] = o;
}

// ---------------------------------------------------------------------------
// bf16 MFMA GEMM: C = A(MxK,row) * Bw(NxK,row)^T + bias.
// Tile 128x128, BK=64, 256 thr = 4 waves (2x2), 4x4 16x16 frags/wave.
// LDS XOR-swizzled (cb ^= (row&7)*16) on write AND read -> conflict-free b128.
// MODE 0: +bias, clip, scatter to Q/K/V (B,H,T,HDIM) fp32.  MODE 1: +bias -> C.
// ---------------------------------------------------------------------------
template<int MODE>
__global__ __launch_bounds__(256)
void gemm_bf16(const ushort* __restrict__ A, const ushort* __restrict__ Bw,
               const float* __restrict__ bias, float* __restrict__ C,
               float* __restrict__ Qb, float* __restrict__ Kb, float* __restrict__ Vb,
               int M, int N, int K)
{
    __shared__ ushort As[128*64];
    __shared__ ushort Bs[128*64];

    const int tid  = threadIdx.x;
    const int wid  = tid >> 6;
    const int lane = tid & 63;
    const int l15  = lane & 15;
    const int l4   = lane >> 4;
    const int wr   = wid >> 1, wc = wid & 1;
    const int row0 = blockIdx.y * 128, col0 = blockIdx.x * 128;

    f32x4 acc[4][4];
    const f32x4 fz = {0.f, 0.f, 0.f, 0.f};
    #pragma unroll
    for (int m = 0; m < 4; ++m)
        #pragma unroll
        for (int n = 0; n < 4; ++n) acc[m][n] = fz;

    for (int kt = 0; kt < K; kt += 64) {
        uint4 ra[4], rb[4];
        #pragma unroll
        for (int q = 0; q < 4; ++q) {
            int idx = q*256 + tid;
            int r = idx >> 3, ch = idx & 7;          // 8 x 16B chunks per 128B row
            ra[q] = *(const uint4*)&A [(size_t)(row0 + r)*K + kt + ch*8];
            rb[q] = *(const uint4*)&Bw[(size_t)(col0 + r)*K + kt + ch*8];
        }
        __syncthreads();
        #pragma unroll
        for (int q = 0; q < 4; ++q) {
            int idx = q*256 + tid;
            int r = idx >> 3, ch = idx & 7;
            int cb = (ch*16) ^ ((r & 7)*16);         // XOR swizzle (write side)
            *(uint4*)((char*)As + r*128 + cb) = ra[q];
            *(uint4*)((char*)Bs + r*128 + cb) = rb[q];
        }
        __syncthreads();
        #pragma unroll
        for (int ks = 0; ks < 2; ++ks) {
            short8 af[4], bf[4];
            const int kb = ks*64 + l4*16;            // byte col of this lane's 8 bf16
            #pragma unroll
            for (int m = 0; m < 4; ++m) {
                int r = wr*64 + m*16 + l15;
                af[m] = *(const short8*)((const char*)As + r*128 + (kb ^ ((r&7)*16)));
            }
            #pragma unroll
            for (int n = 0; n < 4; ++n) {
                int r = wc*64 + n*16 + l15;
                bf[n] = *(const short8*)((const char*)Bs + r*128 + (kb ^ ((r&7)*16)));
            }
            #pragma unroll
            for (int m = 0; m < 4; ++m)
                #pragma unroll
                for (int n = 0; n < 4; ++n)
                    acc[m][n] = __builtin_amdgcn_mfma_f32_16x16x32_bf16(af[m], bf[n], acc[m][n], 0, 0, 0);
        }
    }

    // D layout (m89-verified): col = lane&15, row = (lane>>4)*4 + reg
    if (MODE == 1) {
        #pragma unroll
        for (int n = 0; n < 4; ++n) {
            int col = col0 + wc*64 + n*16 + l15;
            float bv = bias[col];
            #pragma unroll
            for (int m = 0; m < 4; ++m) {
                int rbase = row0 + wr*64 + m*16 + l4*4;
                #pragma unroll
                for (int q = 0; q < 4; ++q)
                    C[(size_t)(rbase + q)*N + col] = acc[m][n][q] + bv;
            }
        }
    } else {
        #pragma unroll
        for (int n = 0; n < 4; ++n) {
            int e  = col0 + wc*64 + n*16 + l15;      // s,h constant per tile (col0 % 128 == 0)
            float bv = bias[e];
            int s = e >> 11, hh = (e >> 7) & 15, d = e & 127;
            float* dst = (s == 0) ? Qb : (s == 1) ? Kb : Vb;
            #pragma unroll
            for (int m = 0; m < 4; ++m) {
                int rbase = row0 + wr*64 + m*16 + l4*4;
                #pragma unroll
                for (int q = 0; q < 4; ++q) {
                    int mg = rbase + q;
                    int b = mg >> 11, t = mg & (T_SEQ - 1);
                    float v = acc[m][n][q] + bv;
                    v = fminf(fmaxf(v, -CLIPV), CLIPV);
                    dst[(size_t)((b*NHEADS + hh)*T_SEQ + t)*HDIM + d] = v;
                }
            }
        }
    }
}

// ---------------------------------------------------------------------------
// RoPE in-place on Q and K (fp32, host sin/cos tables).
// ---------------------------------------------------------------------------
__global__ __launch_bounds__(256)
void rope_kernel(float* __restrict__ Qb, float* __restrict__ Kb,
                 const float* __restrict__ sinT, const float* __restrict__ cosT)
{
    int idx = blockIdx.x * 256 + threadIdx.x;
    int d   = idx & 63;
    int t   = (idx >> 6) & (T_SEQ - 1);
    int bh  = (idx >> 17) & 31;
    float* buf = (idx >> 22) ? Kb : Qb;
    size_t base = ((size_t)bh * T_SEQ + t) * HDIM;
    float c  = cosT[t*64 + d];
    float s  = sinT[t*64 + d];
    float f1 = buf[base + d];
    float f2 = buf[base + 64 + d];
    buf[base + d]      = f1*c - f2*s;
    buf[base + 64 + d] = f1*s + f2*c;
}

// ---------------------------------------------------------------------------
// Causal flash attention, fp32, 512 threads = 8 waves (2 waves/SIMD).
// Q tile 64 rows. Thread (tx=tid&15, ty=tid>>4): S rows {2ty,2ty+1},
// S cols {tx+16*jr}, O cols {4tx..+3, 64+4tx..+3}.
// Ps is wave-local (rows 8w..8w+7 owned by wave w) -> no barrier around softmax.
// T14 async-stage: next K/V global loads issued before compute, LDS-write after.
// Staging map (FIXED from round 2): 4 float4 per thread covers full 64x128 tile.
// Output written directly as bf16 (B,T,D) for the out-projection GEMM.
// ---------------------------------------------------------------------------
__global__ __launch_bounds__(512)
void attn512(const float* __restrict__ Qb, const float* __restrict__ Kb,
             const float* __restrict__ Vb, ushort* __restrict__ att_bf)
{
    __shared__ float Qs[64][132];
    __shared__ float Ks[64][132];
    __shared__ float Vs[64][132];
    __shared__ float Ps[64][65];

    const int tid = threadIdx.x;
    const int tx = tid & 15, ty = tid >> 4;          // ty 0..31
    const int qt = blockIdx.x, h = blockIdx.y, b = blockIdx.z;
    const int bh = b*NHEADS + h;
    const float* Qp = Qb + (size_t)bh*T_SEQ*HDIM + (size_t)qt*64*HDIM;
    const float* Kp = Kb + (size_t)bh*T_SEQ*HDIM;
    const float* Vp = Vb + (size_t)bh*T_SEQ*HDIM;

    // stage Q + K/V tile 0: 64 rows x 128 cols = 2048 float4s, 4 per thread
    #pragma unroll
    for (int l = 0; l < 4; ++l) {
        int idx = l*512 + tid;
        int r   = idx >> 5;            // 0..63
        int c4  = (idx & 31) << 2;     // 0,4,...,124
        *(float4*)&Qs[r][c4] = *(const float4*)&Qp[(size_t)r*HDIM + c4];
        *(float4*)&Ks[r][c4] = *(const float4*)&Kp[(size_t)r*HDIM + c4];
        *(float4*)&Vs[r][c4] = *(const float4*)&Vp[(size_t)r*HDIM + c4];
    }

    float m0 = NEGBIG, m1 = NEGBIG, l0 = 0.f, l1 = 0.f;
    float O0[8], O1[8];
    #pragma unroll
    for (int c = 0; c < 8; ++c) { O0[c] = 0.f; O1[c] = 0.f; }
    const float scale = 0.08838834764831843f;        // 1/sqrt(128)

    for (int kt = 0; kt <= qt; ++kt) {
        __syncthreads();                              // staged K/V (and Q) visible
        const bool more = (kt < qt);
        float4 nK[4], nV[4];
        if (more) {                                   // T14: issue early, write late
            #pragma unroll
            for (int l = 0; l < 4; ++l) {
                int idx = l*512 + tid;
                int r   = idx >> 5;
                int c4  = (idx & 31) << 2;
                nK[l] = *(const float4*)&Kp[(size_t)((kt+1)*64 + r)*HDIM + c4];
                nV[l] = *(const float4*)&Vp[(size_t)((kt+1)*64 + r)*HDIM + c4];
            }
        }

        // ---- S = Q K^T (Q reads broadcast, K reads 2-way free) ----
        float S0[4] = {0.f,0.f,0.f,0.f}, S1[4] = {0.f,0.f,0.f,0.f};
        #pragma unroll 4
        for (int k4 = 0; k4 < 32; ++k4) {
            float4 qa = *(const float4*)&Qs[2*ty  ][k4*4];
            float4 qb = *(const float4*)&Qs[2*ty+1][k4*4];
            #pragma unroll
            for (int jr = 0; jr < 4; ++jr) {
                float4 kv = *(const float4*)&Ks[tx + 16*jr][k4*4];
                S0[jr] = fmaf(qa.x, kv.x, fmaf(qa.y, kv.y, fmaf(qa.z, kv.z, fmaf(qa.w, kv.w, S0[jr]))));
                S1[jr] = fmaf(qb.x, kv.x, fmaf(qb.y, kv.y, fmaf(qb.z, kv.z, fmaf(qb.w, kv.w, S1[jr]))));
            }
        }

        // ---- mask + online softmax (rows wave-local, shfl over 16 tx lanes) ----
        const bool diag = (kt == qt);
        const int rg0 = qt*64 + 2*ty, rg1 = rg0 + 1;
        #pragma unroll
        for (int jr = 0; jr < 4; ++jr) {
            int cg = kt*64 + tx + 16*jr;
            S0[jr] *= scale; S1[jr] *= scale;
            if (diag && cg > rg0) S0[jr] = NEGBIG;
            if (diag && cg > rg1) S1[jr] = NEGBIG;
        }
        float mx0 = fmaxf(fmaxf(S0[0], S0[1]), fmaxf(S0[2], S0[3]));
        float mx1 = fmaxf(fmaxf(S1[0], S1[1]), fmaxf(S1[2], S1[3]));
        #pragma unroll
        for (int msk = 1; msk < 16; msk <<= 1) {
            mx0 = fmaxf(mx0, __shfl_xor(mx0, msk, 64));
            mx1 = fmaxf(mx1, __shfl_xor(mx1, msk, 64));
        }
        float mn0 = fmaxf(m0, mx0), mn1 = fmaxf(m1, mx1);
        float al0 = __expf(m0 - mn0), al1 = __expf(m1 - mn1);
        float ps0 = 0.f, ps1 = 0.f;
        #pragma unroll
        for (int jr = 0; jr < 4; ++jr) {
            float p0 = __expf(S0[jr] - mn0);
            float p1 = __expf(S1[jr] - mn1);
            Ps[2*ty  ][tx + 16*jr] = p0;
            Ps[2*ty+1][tx + 16*jr] = p1;
            ps0 += p0; ps1 += p1;
        }
        #pragma unroll
        for (int msk = 1; msk < 16; msk <<= 1) {
            ps0 += __shfl_xor(ps0, msk, 64);
            ps1 += __shfl_xor(ps1, msk, 64);
        }
        l0 = l0*al0 + ps0; l1 = l1*al1 + ps1;
        m0 = mn0; m1 = mn1;
        #pragma unroll
        for (int c = 0; c < 8; ++c) { O0[c] *= al0; O1[c] *= al1; }

        // ---- O += P V  (Ps reads broadcast; Vs reads 2-way free) ----
        #pragma unroll 4
        for (int j = 0; j < 64; ++j) {
            float p0 = Ps[2*ty][j], p1 = Ps[2*ty+1][j];
            float4 v0 = *(const float4*)&Vs[j][4*tx];
            float4 v1 = *(const float4*)&Vs[j][64 + 4*tx];
            O0[0] = fmaf(p0, v0.x, O0[0]); O0[1] = fmaf(p0, v0.y, O0[1]);
            O0[2] = fmaf(p0, v0.z, O0[2]); O0[3] = fmaf(p0, v0.w, O0[3]);
            O0[4] = fmaf(p0, v1.x, O0[4]); O0[5] = fmaf(p0, v1.y, O0[5]);
            O0[6] = fmaf(p0, v1.z, O0[6]); O0[7] = fmaf(p0, v1.w, O0[7]);
            O1[0] = fmaf(p1, v0.x, O1[0]); O1[1] = fmaf(p1, v0.y, O1[1]);
            O1[2] = fmaf(p1, v0.z, O1[2]); O1[3] = fmaf(p1, v0.w, O1[3]);
            O1[4] = fmaf(p1, v1.x, O1[4]); O1[5] = fmaf(p1, v1.y, O1[5]);
            O1[6] = fmaf(p1, v1.z, O1[6]); O1[7] = fmaf(p1, v1.w, O1[7]);
        }

        __syncthreads();                              // all reads of Ks/Vs done
        if (more) {                                   // T14: late LDS write
            #pragma unroll
            for (int l = 0; l < 4; ++l) {
                int idx = l*512 + tid;
                int r   = idx >> 5;
                int c4  = (idx & 31) << 2;
                *(float4*)&Ks[r][c4] = nK[l];
                *(float4*)&Vs[r][c4] = nV[l];
            }
        }
    }

    // epilogue: att (B,T,D_MODEL) in bf16 for the out-projection
    float inv0 = 1.f / l0, inv1 = 1.f / l1;
    size_t base0 = ((size_t)(b*T_SEQ + qt*64 + 2*ty))*D_MODEL + h*HDIM;
    size_t base1 = base0 + D_MODEL;
    uint2 w;
    w.x = (uint)f2bf(O0[0]*inv0) | ((uint)f2bf(O0[1]*inv0) << 16);
    w.y = (uint)f2bf(O0[2]*inv0) | ((uint)f2bf(O0[3]*inv0) << 16);
    *(uint2*)&att_bf[base0 + 4*tx] = w;
    w.x = (uint)f2bf(O0[4]*inv0) | ((uint)f2bf(O0[5]*inv0) << 16);
    w.y = (uint)f2bf(O0[6]*inv0) | ((uint)f2bf(O0[7]*inv0) << 16);
    *(uint2*)&att_bf[base0 + 64 + 4*tx] = w;
    w.x = (uint)f2bf(O1[0]*inv1) | ((uint)f2bf(O1[1]*inv1) << 16);
    w.y = (uint)f2bf(O1[2]*inv1) | ((uint)f2bf(O1[3]*inv1) << 16);
    *(uint2*)&att_bf[base1 + 4*tx] = w;
    w.x = (uint)f2bf(O1[4]*inv1) | ((uint)f2bf(O1[5]*inv1) << 16);
    w.y = (uint)f2bf(O1[6]*inv1) | ((uint)f2bf(O1[7]*inv1) << 16);
    *(uint2*)&att_bf[base1 + 64 + 4*tx] = w;
}

// ---------------------------------------------------------------------------
extern "C" void kernel_launch(void* const* d_in, const int* in_sizes, int n_in,
                              void* d_out, int out_size, void* d_ws, size_t ws_size,
                              hipStream_t stream)
{
    const float* x     = (const float*)d_in[0];
    const float* w_qkv = (const float*)d_in[1];
    const float* b_qkv = (const float*)d_in[2];
    const float* w_out = (const float*)d_in[3];
    const float* b_out = (const float*)d_in[4];
    const float* psin  = (const float*)d_in[5];
    const float* pcos  = (const float*)d_in[6];
    float* out = (float*)d_out;

    const size_t per = (size_t)BATCH * NHEADS * T_SEQ * HDIM;  // 8,388,608
    float* Qb = (float*)d_ws;
    float* Kb = Qb + per;
    float* Vb = Kb + per;
    ushort* x_bf    = (ushort*)(Vb + per);
    ushort* wqkv_bf = x_bf + (size_t)MROWS*D_MODEL;            // 8.4M
    ushort* wout_bf = wqkv_bf + (size_t)3*D_MODEL*D_MODEL;     // 12.6M
    ushort* att_bf  = wout_bf + (size_t)D_MODEL*D_MODEL;       // 4.2M
    // total ws: ~168 MB

    // 1) fp32 -> bf16 (RNE)
    cvt_bf16<<<(MROWS*D_MODEL/4 + 255)/256, 256, 0, stream>>>(x, x_bf, MROWS*D_MODEL/4);
    cvt_bf16<<<(3*D_MODEL*D_MODEL/4 + 255)/256, 256, 0, stream>>>(w_qkv, wqkv_bf, 3*D_MODEL*D_MODEL/4);
    cvt_bf16<<<(D_MODEL*D_MODEL/4 + 255)/256, 256, 0, stream>>>(w_out, wout_bf, D_MODEL*D_MODEL/4);

    // 2) QKV projection (bf16 MFMA) + bias + clip, scatter to (B,H,T,HDIM) fp32
    gemm_bf16<0><<<dim3(3*D_MODEL/128, MROWS/128), 256, 0, stream>>>(
        x_bf, wqkv_bf, b_qkv, nullptr, Qb, Kb, Vb, MROWS, 3*D_MODEL, D_MODEL);

    // 3) RoPE (fp32)
    rope_kernel<<<(2u*BATCH*NHEADS*T_SEQ*64)/256, 256, 0, stream>>>(Qb, Kb, psin, pcos);

    // 4) causal flash attention (fp32 compute, bf16 output)
    attn512<<<dim3(T_SEQ/64, NHEADS, BATCH), 512, 0, stream>>>(Qb, Kb, Vb, att_bf);

    // 5) output projection (bf16 MFMA) + bias
    gemm_bf16<1><<<dim3(D_MODEL/128, MROWS/128), 256, 0, stream>>>(
        att_bf, wout_bf, b_out, out, nullptr, nullptr, nullptr, MROWS, D_MODEL, D_MODEL);
}

// Round 4
// 1183.268 us; speedup vs baseline: 2.9577x; 1.8124x over previous
//
#include <hip/hip_runtime.h>
#include <math.h>

#define D_MODEL 2048
#define T_SEQ   2048
#define BATCH   2
#define NHEADS  16
#define HDIM    128
#define MROWS   (BATCH*T_SEQ)   // 4096
#define CLIPV   8.0f
#define NEGBIG  (-1e30f)

typedef __attribute__((ext_vector_type(8))) short short8;   // 8 bf16 = 4 VGPR (MFMA A/B frag)
typedef __attribute__((ext_vector_type(4))) float f32x4;    // MFMA C/D frag

__device__ inline ushort f2bf(float f) {                    // fp32 -> bf16 RNE
    uint32_t u = __float_as_uint(f);
    return (ushort)((u + 0x7fffu + ((u >> 16) & 1u)) >> 16);
}

// ---------------------------------------------------------------------------
// fp32 -> bf16 convert, float4 in / ushort4 out
// ---------------------------------------------------------------------------
__global__ __launch_bounds__(256)
void cvt_bf16(const float* __restrict__ in, ushort* __restrict__ out, int n4)
{
    int i = blockIdx.x * 256 + threadIdx.x;
    if (i >= n4) return;
    float4 v = ((const float4*)in)[i];
    ushort4 o;
    o.x = f2bf(v.x); o.y = f2bf(v.y); o.z = f2bf(v.z); o.w = f2bf(v.w);
    ((ushort4*)out)[i] = o;
}

// ---------------------------------------------------------------------------
// bf16 MFMA GEMM: C = A(MxK,row) * Bw(NxK,row)^T + bias.   (validated round 3)
// Tile 128x128, BK=64, 256 thr = 4 waves (2x2), 4x4 16x16 frags/wave.
// MODE 0: +bias, clip, scatter to Q/K/V (B,H,T,HDIM) fp32.  MODE 1: +bias -> C.
// ---------------------------------------------------------------------------
template<int MODE>
__global__ __launch_bounds__(256)
void gemm_bf16(const ushort* __restrict__ A, const ushort* __restrict__ Bw,
               const float* __restrict__ bias, float* __restrict__ C,
               float* __restrict__ Qb, float* __restrict__ Kb, float* __restrict__ Vb,
               int M, int N, int K)
{
    __shared__ ushort As[128*64];
    __shared__ ushort Bs[128*64];

    const int tid  = threadIdx.x;
    const int wid  = tid >> 6;
    const int lane = tid & 63;
    const int l15  = lane & 15;
    const int l4   = lane >> 4;
    const int wr   = wid >> 1, wc = wid & 1;
    const int row0 = blockIdx.y * 128, col0 = blockIdx.x * 128;

    f32x4 acc[4][4];
    const f32x4 fz = {0.f, 0.f, 0.f, 0.f};
    #pragma unroll
    for (int m = 0; m < 4; ++m)
        #pragma unroll
        for (int n = 0; n < 4; ++n) acc[m][n] = fz;

    for (int kt = 0; kt < K; kt += 64) {
        uint4 ra[4], rb[4];
        #pragma unroll
        for (int q = 0; q < 4; ++q) {
            int idx = q*256 + tid;
            int r = idx >> 3, ch = idx & 7;
            ra[q] = *(const uint4*)&A [(size_t)(row0 + r)*K + kt + ch*8];
            rb[q] = *(const uint4*)&Bw[(size_t)(col0 + r)*K + kt + ch*8];
        }
        __syncthreads();
        #pragma unroll
        for (int q = 0; q < 4; ++q) {
            int idx = q*256 + tid;
            int r = idx >> 3, ch = idx & 7;
            int cb = (ch*16) ^ ((r & 7)*16);
            *(uint4*)((char*)As + r*128 + cb) = ra[q];
            *(uint4*)((char*)Bs + r*128 + cb) = rb[q];
        }
        __syncthreads();
        #pragma unroll
        for (int ks = 0; ks < 2; ++ks) {
            short8 af[4], bf[4];
            const int kb = ks*64 + l4*16;
            #pragma unroll
            for (int m = 0; m < 4; ++m) {
                int r = wr*64 + m*16 + l15;
                af[m] = *(const short8*)((const char*)As + r*128 + (kb ^ ((r&7)*16)));
            }
            #pragma unroll
            for (int n = 0; n < 4; ++n) {
                int r = wc*64 + n*16 + l15;
                bf[n] = *(const short8*)((const char*)Bs + r*128 + (kb ^ ((r&7)*16)));
            }
            #pragma unroll
            for (int m = 0; m < 4; ++m)
                #pragma unroll
                for (int n = 0; n < 4; ++n)
                    acc[m][n] = __builtin_amdgcn_mfma_f32_16x16x32_bf16(af[m], bf[n], acc[m][n], 0, 0, 0);
        }
    }

    if (MODE == 1) {
        #pragma unroll
        for (int n = 0; n < 4; ++n) {
            int col = col0 + wc*64 + n*16 + l15;
            float bv = bias[col];
            #pragma unroll
            for (int m = 0; m < 4; ++m) {
                int rbase = row0 + wr*64 + m*16 + l4*4;
                #pragma unroll
                for (int q = 0; q < 4; ++q)
                    C[(size_t)(rbase + q)*N + col] = acc[m][n][q] + bv;
            }
        }
    } else {
        #pragma unroll
        for (int n = 0; n < 4; ++n) {
            int e  = col0 + wc*64 + n*16 + l15;
            float bv = bias[e];
            int s = e >> 11, hh = (e >> 7) & 15, d = e & 127;
            float* dst = (s == 0) ? Qb : (s == 1) ? Kb : Vb;
            #pragma unroll
            for (int m = 0; m < 4; ++m) {
                int rbase = row0 + wr*64 + m*16 + l4*4;
                #pragma unroll
                for (int q = 0; q < 4; ++q) {
                    int mg = rbase + q;
                    int b = mg >> 11, t = mg & (T_SEQ - 1);
                    float v = acc[m][n][q] + bv;
                    v = fminf(fmaxf(v, -CLIPV), CLIPV);
                    dst[(size_t)((b*NHEADS + hh)*T_SEQ + t)*HDIM + d] = v;
                }
            }
        }
    }
}

// ---------------------------------------------------------------------------
// RoPE on Q and K (fp32 in, (B,H,T,HDIM)) -> bf16 out, same layout.
// ---------------------------------------------------------------------------
__global__ __launch_bounds__(256)
void rope_bf16(const float* __restrict__ Qb, const float* __restrict__ Kb,
               ushort* __restrict__ Qo, ushort* __restrict__ Ko,
               const float* __restrict__ sinT, const float* __restrict__ cosT)
{
    int idx = blockIdx.x * 256 + threadIdx.x;
    int d   = idx & 63;
    int t   = (idx >> 6) & (T_SEQ - 1);
    int bh  = (idx >> 17) & 31;
    const float* src = (idx >> 22) ? Kb : Qb;
    ushort*      dst = (idx >> 22) ? Ko : Qo;
    size_t base = ((size_t)bh * T_SEQ + t) * HDIM;
    float c  = cosT[t*64 + d];
    float s  = sinT[t*64 + d];
    float f1 = src[base + d];
    float f2 = src[base + 64 + d];
    dst[base + d]      = f2bf(f1*c - f2*s);
    dst[base + 64 + d] = f2bf(f1*s + f2*c);
}

// ---------------------------------------------------------------------------
// V (B,H,T,128) fp32 -> Vt (B,H,128,T) bf16, 32t x 128d LDS tile per block.
// ---------------------------------------------------------------------------
__global__ __launch_bounds__(256)
void vt_kernel(const float* __restrict__ Vb, ushort* __restrict__ Vt)
{
    __shared__ float tile[32][132];
    const int tid = threadIdx.x;
    const int t0  = blockIdx.x * 32;
    const int bh  = blockIdx.y;
    const float* src = Vb + ((size_t)bh*T_SEQ + t0)*HDIM;
    #pragma unroll
    for (int l = 0; l < 4; ++l) {
        int idx = l*256 + tid;
        int r = idx >> 5, c4 = (idx & 31) << 2;
        *(float4*)&tile[r][c4] = *(const float4*)&src[(size_t)r*HDIM + c4];
    }
    __syncthreads();
    ushort* dst = Vt + (size_t)bh*HDIM*T_SEQ;
    #pragma unroll
    for (int l = 0; l < 8; ++l) {
        int o = l*256 + tid;
        int d = o >> 4, tp = (o & 15) << 1;
        uint v = (uint)f2bf(tile[tp][d]) | ((uint)f2bf(tile[tp+1][d]) << 16);
        *(uint*)&dst[(size_t)d*T_SEQ + t0 + tp] = v;
    }
}

// ---------------------------------------------------------------------------
// Causal flash attention, bf16 MFMA. 256 thr = 4 waves; Q tile 64 (16 rows
// per wave, Q in registers), KV tile 64. K/Vt in XOR-swizzled LDS; P goes
// through a per-wave swizzled LDS buffer (D-layout -> A-layout). fp32
// softmax state + fp32 MFMA accumulators. T14 reg-prefetch of next tiles.
// Fragment mappings identical to the (validated) gemm_bf16.
// ---------------------------------------------------------------------------
__global__ __launch_bounds__(256, 3)
void attn_mfma(const ushort* __restrict__ Qbf, const ushort* __restrict__ Kbf,
               const ushort* __restrict__ Vtbf, ushort* __restrict__ att_bf)
{
    __shared__ ushort Ks [64*128];     // 16 KB, swizzled: row*256B, col ^ (row&7)<<4
    __shared__ ushort Vts[128*64];     // 16 KB, swizzled: row*128B (row = d)
    __shared__ ushort Plds[4][16*64];  // 2 KB per wave, swizzled

    const int tid  = threadIdx.x;
    const int w    = tid >> 6;
    const int lane = tid & 63;
    const int l15  = lane & 15, l4 = lane >> 4;
    const int qt = blockIdx.x, h = blockIdx.y, b = blockIdx.z;
    const int bh = b*NHEADS + h;

    const ushort* Qp = Qbf + ((size_t)bh*T_SEQ + qt*64 + w*16)*HDIM;
    const ushort* Kp = Kbf  + (size_t)bh*T_SEQ*HDIM;
    const ushort* Vp = Vtbf + (size_t)bh*HDIM*T_SEQ;

    // Q fragments in registers: A-frag row=l15, k = kk*32 + l4*8
    short8 qf[4];
    #pragma unroll
    for (int kk = 0; kk < 4; ++kk)
        qf[kk] = *(const short8*)&Qp[(size_t)l15*HDIM + kk*32 + l4*8];

    // stage K/Vt tile 0 (K: 64r x 16 chunks; Vt: 128r x 8 chunks)
    #pragma unroll
    for (int l = 0; l < 4; ++l) {
        int idx = l*256 + tid;
        int rk = idx >> 4, ck = idx & 15;
        *(uint4*)((char*)Ks + rk*256 + ((ck*16) ^ ((rk&7)<<4))) =
            *(const uint4*)&Kp[(size_t)rk*HDIM + ck*8];
        int rv = idx >> 3, cv = idx & 7;
        *(uint4*)((char*)Vts + rv*128 + ((cv*16) ^ ((rv&7)<<4))) =
            *(const uint4*)&Vp[(size_t)rv*T_SEQ + cv*8];
    }

    f32x4 of[8];
    const f32x4 fz = {0.f,0.f,0.f,0.f};
    #pragma unroll
    for (int df = 0; df < 8; ++df) of[df] = fz;
    float m_run[4] = {NEGBIG,NEGBIG,NEGBIG,NEGBIG};
    float l_run[4] = {0.f,0.f,0.f,0.f};
    const float scale = 0.08838834764831843f;   // 1/sqrt(128)
    char* Pw = (char*)Plds[w];

    __syncthreads();

    for (int kt = 0; kt <= qt; ++kt) {
        const bool more = (kt < qt);
        uint4 pk[4], pv[4];
        if (more) {                               // T14: issue early, write late
            #pragma unroll
            for (int l = 0; l < 4; ++l) {
                int idx = l*256 + tid;
                int rk = idx >> 4, ck = idx & 15;
                pk[l] = *(const uint4*)&Kp[(size_t)((kt+1)*64 + rk)*HDIM + ck*8];
                int rv = idx >> 3, cv = idx & 7;
                pv[l] = *(const uint4*)&Vp[(size_t)rv*T_SEQ + (kt+1)*64 + cv*8];
            }
        }

        // ---- S = Q K^T : 4 col-frags x 4 k-steps ----
        f32x4 sf[4];
        #pragma unroll
        for (int n = 0; n < 4; ++n) sf[n] = fz;
        #pragma unroll
        for (int n = 0; n < 4; ++n) {
            int row = n*16 + l15;                 // key index = output col
            int swz = (row & 7) << 4;
            #pragma unroll
            for (int kk = 0; kk < 4; ++kk) {
                short8 kf = *(const short8*)((char*)Ks + row*256 + ((kk*64 + l4*16) ^ swz));
                sf[n] = __builtin_amdgcn_mfma_f32_16x16x32_bf16(qf[kk], kf, sf[n], 0, 0, 0);
            }
        }

        // ---- scale + causal mask + row max (rows = l4*4+reg) ----
        const bool diag = (kt == qt);
        float mx[4], al[4], ps[4];
        #pragma unroll
        for (int reg = 0; reg < 4; ++reg) {
            int qg = qt*64 + w*16 + l4*4 + reg;
            float m = NEGBIG;
            #pragma unroll
            for (int n = 0; n < 4; ++n) {
                float s = sf[n][reg] * scale;
                if (diag && (kt*64 + n*16 + l15) > qg) s = NEGBIG;
                sf[n][reg] = s;
                m = fmaxf(m, s);
            }
            mx[reg] = m;
        }
        #pragma unroll
        for (int msk = 1; msk < 16; msk <<= 1) {
            #pragma unroll
            for (int reg = 0; reg < 4; ++reg)
                mx[reg] = fmaxf(mx[reg], __shfl_xor(mx[reg], msk, 64));
        }

        // ---- P = exp(S-m), write bf16 to per-wave LDS (swizzled) ----
        #pragma unroll
        for (int reg = 0; reg < 4; ++reg) {
            float mn = fmaxf(m_run[reg], mx[reg]);
            al[reg] = __expf(m_run[reg] - mn);
            m_run[reg] = mn;
            int prow = l4*4 + reg;
            int pswz = (prow & 7) << 4;
            float s = 0.f;
            #pragma unroll
            for (int n = 0; n < 4; ++n) {
                float p = __expf(sf[n][reg] - mn);
                s += p;
                *(ushort*)(Pw + prow*128 + (((n*16 + l15)*2) ^ pswz)) = f2bf(p);
            }
            ps[reg] = s;
        }
        #pragma unroll
        for (int msk = 1; msk < 16; msk <<= 1) {
            #pragma unroll
            for (int reg = 0; reg < 4; ++reg)
                ps[reg] += __shfl_xor(ps[reg], msk, 64);
        }
        #pragma unroll
        for (int reg = 0; reg < 4; ++reg)
            l_run[reg] = l_run[reg]*al[reg] + ps[reg];
        #pragma unroll
        for (int df = 0; df < 8; ++df)
            #pragma unroll
            for (int reg = 0; reg < 4; ++reg)
                of[df][reg] *= al[reg];

        // ---- O += P V : P A-frags from Plds, V B-frags from Vts ----
        #pragma unroll
        for (int ks = 0; ks < 2; ++ks) {
            short8 pa = *(const short8*)(Pw + l15*128 + ((ks*64 + l4*16) ^ ((l15&7)<<4)));
            #pragma unroll
            for (int df = 0; df < 8; ++df) {
                int row = df*16 + l15;            // d index = output col
                short8 vf = *(const short8*)((char*)Vts + row*128 + ((ks*64 + l4*16) ^ ((row&7)<<4)));
                of[df] = __builtin_amdgcn_mfma_f32_16x16x32_bf16(pa, vf, of[df], 0, 0, 0);
            }
        }

        __syncthreads();                          // all waves done reading Ks/Vts
        if (more) {                               // T14: late LDS write
            #pragma unroll
            for (int l = 0; l < 4; ++l) {
                int idx = l*256 + tid;
                int rk = idx >> 4, ck = idx & 15;
                *(uint4*)((char*)Ks + rk*256 + ((ck*16) ^ ((rk&7)<<4))) = pk[l];
                int rv = idx >> 3, cv = idx & 7;
                *(uint4*)((char*)Vts + rv*128 + ((cv*16) ^ ((rv&7)<<4))) = pv[l];
            }
        }
        __syncthreads();
    }

    // ---- epilogue: O/l -> att_bf (B,T,D_MODEL) bf16 ----
    float inv[4];
    #pragma unroll
    for (int reg = 0; reg < 4; ++reg) inv[reg] = 1.f / l_run[reg];
    #pragma unroll
    for (int df = 0; df < 8; ++df) {
        #pragma unroll
        for (int reg = 0; reg < 4; ++reg) {
            int t = qt*64 + w*16 + l4*4 + reg;
            att_bf[((size_t)(b*T_SEQ + t))*D_MODEL + h*HDIM + df*16 + l15] =
                f2bf(of[df][reg] * inv[reg]);
        }
    }
}

// ---------------------------------------------------------------------------
extern "C" void kernel_launch(void* const* d_in, const int* in_sizes, int n_in,
                              void* d_out, int out_size, void* d_ws, size_t ws_size,
                              hipStream_t stream)
{
    const float* x     = (const float*)d_in[0];
    const float* w_qkv = (const float*)d_in[1];
    const float* b_qkv = (const float*)d_in[2];
    const float* w_out = (const float*)d_in[3];
    const float* b_out = (const float*)d_in[4];
    const float* psin  = (const float*)d_in[5];
    const float* pcos  = (const float*)d_in[6];
    float* out = (float*)d_out;

    const size_t per = (size_t)BATCH * NHEADS * T_SEQ * HDIM;  // 8,388,608
    float* Qb = (float*)d_ws;
    float* Kb = Qb + per;
    float* Vb = Kb + per;
    ushort* x_bf    = (ushort*)(Vb + per);
    ushort* wqkv_bf = x_bf + (size_t)MROWS*D_MODEL;
    ushort* wout_bf = wqkv_bf + (size_t)3*D_MODEL*D_MODEL;
    ushort* att_bf  = wout_bf + (size_t)D_MODEL*D_MODEL;
    ushort* Qbf     = att_bf + (size_t)MROWS*D_MODEL;
    ushort* Kbf     = Qbf + per;
    ushort* Vt      = Kbf + per;
    // total ws: ~218 MB

    // 1) fp32 -> bf16 (RNE) for GEMM operands
    cvt_bf16<<<(MROWS*D_MODEL/4 + 255)/256, 256, 0, stream>>>(x, x_bf, MROWS*D_MODEL/4);
    cvt_bf16<<<(3*D_MODEL*D_MODEL/4 + 255)/256, 256, 0, stream>>>(w_qkv, wqkv_bf, 3*D_MODEL*D_MODEL/4);
    cvt_bf16<<<(D_MODEL*D_MODEL/4 + 255)/256, 256, 0, stream>>>(w_out, wout_bf, D_MODEL*D_MODEL/4);

    // 2) QKV projection (bf16 MFMA) + bias + clip, scatter fp32 (B,H,T,HDIM)
    gemm_bf16<0><<<dim3(3*D_MODEL/128, MROWS/128), 256, 0, stream>>>(
        x_bf, wqkv_bf, b_qkv, nullptr, Qb, Kb, Vb, MROWS, 3*D_MODEL, D_MODEL);

    // 3) RoPE -> bf16 Q/K ; V -> bf16 transposed (B,H,128,T)
    rope_bf16<<<(2u*BATCH*NHEADS*T_SEQ*64)/256, 256, 0, stream>>>(Qb, Kb, Qbf, Kbf, psin, pcos);
    vt_kernel<<<dim3(T_SEQ/32, BATCH*NHEADS), 256, 0, stream>>>(Vb, Vt);

    // 4) causal flash attention (bf16 MFMA, fp32 softmax)
    attn_mfma<<<dim3(T_SEQ/64, NHEADS, BATCH), 256, 0, stream>>>(Qbf, Kbf, Vt, att_bf);

    // 5) output projection (bf16 MFMA) + bias
    gemm_bf16<1><<<dim3(D_MODEL/128, MROWS/128), 256, 0, stream>>>(
        att_bf, wout_bf, b_out, out, nullptr, nullptr, nullptr, MROWS, D_MODEL, D_MODEL);
}

// Round 6
// 532.123 us; speedup vs baseline: 6.5770x; 2.2237x over previous
//
#include <hip/hip_runtime.h>
#include <math.h>

#define D_MODEL 2048
#define T_SEQ   2048
#define BATCH   2
#define NHEADS  16
#define HDIM    128
#define MROWS   (BATCH*T_SEQ)   // 4096
#define CLIPV   8.0f
#define NEGBIG  (-1e30f)

typedef __attribute__((ext_vector_type(8))) short short8;   // 8 bf16 = 4 VGPR (MFMA A/B frag)
typedef __attribute__((ext_vector_type(4))) float f32x4;    // MFMA C/D frag

__device__ inline ushort f2bf(float f) {                    // fp32 -> bf16 RNE
    uint32_t u = __float_as_uint(f);
    return (ushort)((u + 0x7fffu + ((u >> 16) & 1u)) >> 16);
}

// async global->LDS, 16B per lane. LDS dest = wave-uniform base + lane*16.
__device__ inline void gload_lds16(const void* g, void* l) {
    __builtin_amdgcn_global_load_lds(
        (const __attribute__((address_space(1))) void*)g,
        (__attribute__((address_space(3))) void*)l, 16, 0, 0);
}

// ---------------------------------------------------------------------------
// fp32 -> bf16 convert
// ---------------------------------------------------------------------------
__global__ __launch_bounds__(256)
void cvt_bf16(const float* __restrict__ in, ushort* __restrict__ out, int n4)
{
    int i = blockIdx.x * 256 + threadIdx.x;
    if (i >= n4) return;
    float4 v = ((const float4*)in)[i];
    ushort4 o;
    o.x = f2bf(v.x); o.y = f2bf(v.y); o.z = f2bf(v.z); o.w = f2bf(v.w);
    ((ushort4*)out)[i] = o;
}

// ---------------------------------------------------------------------------
// bf16 MFMA GEMM: C = A(MxK,row) * Bw(NxK,row)^T + bias.
// Tile 128x128, BK=64, 256 thr = 4 waves (2x2), 4x4 16x16 frags/wave.
// Staging: global_load_lds w=16, pre-swizzled SOURCE chunk (ch ^ (r&7)),
// linear LDS dest -> LDS holds the XOR-swizzled layout; reads unchanged.
// MFMA operands SWAPPED: acc[m][n]=mfma(bf[n],af[m]) -> lane owns
// row = m*16+l15 (one C row), cols = n*16+l4*4..+3 -> float4 stores.
// ---------------------------------------------------------------------------
template<int MODE>
__global__ __launch_bounds__(256)
void gemm_bf16(const ushort* __restrict__ A, const ushort* __restrict__ Bw,
               const float* __restrict__ bias, float* __restrict__ C,
               float* __restrict__ Qb, float* __restrict__ Kb, float* __restrict__ Vb,
               int M, int N, int K)
{
    __shared__ ushort As[128*64];
    __shared__ ushort Bs[128*64];

    const int tid  = threadIdx.x;
    const int wid  = tid >> 6;
    const int lane = tid & 63;
    const int l15  = lane & 15;
    const int l4   = lane >> 4;
    const int wr   = wid >> 1, wc = wid & 1;
    const int row0 = blockIdx.y * 128, col0 = blockIdx.x * 128;

    const int r_st  = tid >> 3;          // 0..31 (row within 128 per q-step of 32)
    const int ch    = tid & 7;           // 16B chunk 0..7 (64 bf16 = BK)
    const int wbase = tid & ~63;         // wave-uniform

    f32x4 acc[4][4];
    const f32x4 fz = {0.f, 0.f, 0.f, 0.f};
    #pragma unroll
    for (int m = 0; m < 4; ++m)
        #pragma unroll
        for (int n = 0; n < 4; ++n) acc[m][n] = fz;

    for (int kt = 0; kt < K; kt += 64) {
        // issue async staging: 4 q-steps x (A,B); source chunk pre-swizzled
        #pragma unroll
        for (int q = 0; q < 4; ++q) {
            int r   = q*32 + r_st;
            int chs = ch ^ (r & 7);
            gload_lds16(&A [(size_t)(row0 + r)*K + kt + chs*8],
                        (char*)As + (q*256 + wbase)*16);
            gload_lds16(&Bw[(size_t)(col0 + r)*K + kt + chs*8],
                        (char*)Bs + (q*256 + wbase)*16);
        }
        __syncthreads();                 // drains vmcnt(0): staged data visible
        #pragma unroll
        for (int ks = 0; ks < 2; ++ks) {
            short8 af[4], bf[4];
            const int kb = ks*64 + l4*16;
            #pragma unroll
            for (int m = 0; m < 4; ++m) {
                int r = wr*64 + m*16 + l15;
                af[m] = *(const short8*)((const char*)As + r*128 + (kb ^ ((r&7)*16)));
            }
            #pragma unroll
            for (int n = 0; n < 4; ++n) {
                int r = wc*64 + n*16 + l15;
                bf[n] = *(const short8*)((const char*)Bs + r*128 + (kb ^ ((r&7)*16)));
            }
            #pragma unroll
            for (int m = 0; m < 4; ++m)
                #pragma unroll
                for (int n = 0; n < 4; ++n)   // SWAPPED operand order
                    acc[m][n] = __builtin_amdgcn_mfma_f32_16x16x32_bf16(bf[n], af[m], acc[m][n], 0, 0, 0);
        }
        __syncthreads();                 // all reads done before next staging
    }

    // Swapped D layout: C row = row0+wr*64+m*16+l15 ; cols = col0+wc*64+n*16+l4*4..+3
    if (MODE == 1) {
        float4 bv[4];
        #pragma unroll
        for (int n = 0; n < 4; ++n)
            bv[n] = *(const float4*)&bias[col0 + wc*64 + n*16 + l4*4];
        #pragma unroll
        for (int m = 0; m < 4; ++m) {
            int row = row0 + wr*64 + m*16 + l15;
            #pragma unroll
            for (int n = 0; n < 4; ++n) {
                int col = col0 + wc*64 + n*16 + l4*4;
                float4 o;
                o.x = acc[m][n][0] + bv[n].x;
                o.y = acc[m][n][1] + bv[n].y;
                o.z = acc[m][n][2] + bv[n].z;
                o.w = acc[m][n][3] + bv[n].w;
                *(float4*)&C[(size_t)row*N + col] = o;
            }
        }
    } else {
        float4 bv[4];
        #pragma unroll
        for (int n = 0; n < 4; ++n)
            bv[n] = *(const float4*)&bias[col0 + wc*64 + n*16 + l4*4];
        #pragma unroll
        for (int m = 0; m < 4; ++m) {
            int mg = row0 + wr*64 + m*16 + l15;
            int b = mg >> 11, t = mg & (T_SEQ - 1);
            #pragma unroll
            for (int n = 0; n < 4; ++n) {
                int e  = col0 + wc*64 + n*16 + l4*4;
                int s = e >> 11, hh = (e >> 7) & 15, d = e & 127;
                float* dst = (s == 0) ? Qb : (s == 1) ? Kb : Vb;
                float4 o;
                o.x = fminf(fmaxf(acc[m][n][0] + bv[n].x, -CLIPV), CLIPV);
                o.y = fminf(fmaxf(acc[m][n][1] + bv[n].y, -CLIPV), CLIPV);
                o.z = fminf(fmaxf(acc[m][n][2] + bv[n].z, -CLIPV), CLIPV);
                o.w = fminf(fmaxf(acc[m][n][3] + bv[n].w, -CLIPV), CLIPV);
                *(float4*)&dst[(size_t)((b*NHEADS + hh)*T_SEQ + t)*HDIM + d] = o;
            }
        }
    }
}

// ---------------------------------------------------------------------------
// RoPE on Q and K (fp32 in, (B,H,T,HDIM)) -> bf16 out, same layout.
// ---------------------------------------------------------------------------
__global__ __launch_bounds__(256)
void rope_bf16(const float* __restrict__ Qb, const float* __restrict__ Kb,
               ushort* __restrict__ Qo, ushort* __restrict__ Ko,
               const float* __restrict__ sinT, const float* __restrict__ cosT)
{
    int idx = blockIdx.x * 256 + threadIdx.x;
    int d   = idx & 63;
    int t   = (idx >> 6) & (T_SEQ - 1);
    int bh  = (idx >> 17) & 31;
    const float* src = (idx >> 22) ? Kb : Qb;
    ushort*      dst = (idx >> 22) ? Ko : Qo;
    size_t base = ((size_t)bh * T_SEQ + t) * HDIM;
    float c  = cosT[t*64 + d];
    float s  = sinT[t*64 + d];
    float f1 = src[base + d];
    float f2 = src[base + 64 + d];
    dst[base + d]      = f2bf(f1*c - f2*s);
    dst[base + 64 + d] = f2bf(f1*s + f2*c);
}

// ---------------------------------------------------------------------------
// V (B,H,T,128) fp32 -> Vt (B,H,128,T) bf16
// ---------------------------------------------------------------------------
__global__ __launch_bounds__(256)
void vt_kernel(const float* __restrict__ Vb, ushort* __restrict__ Vt)
{
    __shared__ float tile[32][132];
    const int tid = threadIdx.x;
    const int t0  = blockIdx.x * 32;
    const int bh  = blockIdx.y;
    const float* src = Vb + ((size_t)bh*T_SEQ + t0)*HDIM;
    #pragma unroll
    for (int l = 0; l < 4; ++l) {
        int idx = l*256 + tid;
        int r = idx >> 5, c4 = (idx & 31) << 2;
        *(float4*)&tile[r][c4] = *(const float4*)&src[(size_t)r*HDIM + c4];
    }
    __syncthreads();
    ushort* dst = Vt + (size_t)bh*HDIM*T_SEQ;
    #pragma unroll
    for (int l = 0; l < 8; ++l) {
        int o = l*256 + tid;
        int d = o >> 4, tp = (o & 15) << 1;
        uint v = (uint)f2bf(tile[tp][d]) | ((uint)f2bf(tile[tp+1][d]) << 16);
        *(uint*)&dst[(size_t)d*T_SEQ + t0 + tp] = v;
    }
}

// ---------------------------------------------------------------------------
// Causal flash attention, bf16 MFMA, SWAPPED operands throughout:
//  - S^T = mfma(K,Q): lane owns ONE q row (l15), 16 j's (n,l4*4+reg)
//    -> scalar m/l state, in-lane row reduce + 2 shfls
//  - O^T = mfma(V,P): lane owns q row l15, d = df*16+l4*4+reg -> uint2 stores
// Causal PAIRING: block handles q-tiles {pr, 31-pr} -> constant 33 KV iters.
// K/Vt XOR-swizzled LDS; P per-wave LDS roundtrip; T14 reg-prefetch.
// ---------------------------------------------------------------------------
__global__ __launch_bounds__(256, 2)
void attn_mfma(const ushort* __restrict__ Qbf, const ushort* __restrict__ Kbf,
               const ushort* __restrict__ Vtbf, ushort* __restrict__ att_bf)
{
    __shared__ ushort Ks [64*128];     // 16 KB: row(key)*256B, chunk ^ (row&7)<<4
    __shared__ ushort Vts[128*64];     // 16 KB: row(d)*128B,  chunk ^ (row&7)<<4
    __shared__ ushort Plds[4][16*64];  // 8 KB: per-wave P[q][j]

    const int tid  = threadIdx.x;
    const int w    = tid >> 6;
    const int lane = tid & 63;
    const int l15  = lane & 15, l4 = lane >> 4;
    const int pr = blockIdx.x, h = blockIdx.y, b = blockIdx.z;
    const int bh = b*NHEADS + h;
    const ushort* Kp = Kbf  + (size_t)bh*T_SEQ*HDIM;
    const ushort* Vp = Vtbf + (size_t)bh*HDIM*T_SEQ;
    char* Pw = (char*)Plds[w];
    const float scale = 0.08838834764831843f;   // 1/sqrt(128)
    const int pswz = (l15 & 7) << 4;

    #pragma unroll
    for (int ph = 0; ph < 2; ++ph) {
        const int qt = ph ? (T_SEQ/64 - 1 - pr) : pr;

        // Q fragments in registers: q row = l15, k = kk*32 + l4*8
        const ushort* Qp = Qbf + ((size_t)bh*T_SEQ + qt*64 + w*16)*HDIM;
        short8 qf[4];
        #pragma unroll
        for (int kk = 0; kk < 4; ++kk)
            qf[kk] = *(const short8*)&Qp[(size_t)l15*HDIM + kk*32 + l4*8];

        // stage K/Vt tile 0 (prev phase's reads all done: loop ends with barrier)
        #pragma unroll
        for (int l = 0; l < 4; ++l) {
            int idx = l*256 + tid;
            int rk = idx >> 4, ck = idx & 15;
            *(uint4*)((char*)Ks + rk*256 + ((ck*16) ^ ((rk&7)<<4))) =
                *(const uint4*)&Kp[(size_t)rk*HDIM + ck*8];
            int rv = idx >> 3, cv = idx & 7;
            *(uint4*)((char*)Vts + rv*128 + ((cv*16) ^ ((rv&7)<<4))) =
                *(const uint4*)&Vp[(size_t)rv*T_SEQ + cv*8];
        }

        f32x4 of[8];
        const f32x4 fz = {0.f,0.f,0.f,0.f};
        #pragma unroll
        for (int df = 0; df < 8; ++df) of[df] = fz;
        float m_run = NEGBIG, l_run = 0.f;
        const int qg = qt*64 + w*16 + l15;     // this lane's global q row

        __syncthreads();

        for (int kt = 0; kt <= qt; ++kt) {
            const bool more = (kt < qt);
            uint4 pk[4], pv[4];
            if (more) {                        // T14: issue early, write late
                #pragma unroll
                for (int l = 0; l < 4; ++l) {
                    int idx = l*256 + tid;
                    int rk = idx >> 4, ck = idx & 15;
                    pk[l] = *(const uint4*)&Kp[(size_t)((kt+1)*64 + rk)*HDIM + ck*8];
                    int rv = idx >> 3, cv = idx & 7;
                    pv[l] = *(const uint4*)&Vp[(size_t)rv*T_SEQ + (kt+1)*64 + cv*8];
                }
            }

            // ---- S^T = K Q^T : lane owns q row l15, j = n*16 + l4*4 + reg ----
            f32x4 ss[4];
            #pragma unroll
            for (int n = 0; n < 4; ++n) ss[n] = fz;
            #pragma unroll
            for (int n = 0; n < 4; ++n) {
                int row = n*16 + l15;          // key row in frag
                int swz = (row & 7) << 4;
                #pragma unroll
                for (int kk = 0; kk < 4; ++kk) {
                    short8 kf = *(const short8*)((char*)Ks + row*256 + ((kk*64 + l4*16) ^ swz));
                    ss[n] = __builtin_amdgcn_mfma_f32_16x16x32_bf16(kf, qf[kk], ss[n], 0, 0, 0);
                }
            }

            // ---- scale + mask + row max (in-lane over 16, then 2 shfls) ----
            const bool diag = (kt == qt);
            float mx = NEGBIG;
            #pragma unroll
            for (int n = 0; n < 4; ++n)
                #pragma unroll
                for (int reg = 0; reg < 4; ++reg) {
                    float s = ss[n][reg] * scale;
                    int j = kt*64 + n*16 + l4*4 + reg;
                    if (diag && j > qg) s = NEGBIG;
                    ss[n][reg] = s;
                    mx = fmaxf(mx, s);
                }
            mx = fmaxf(mx, __shfl_xor(mx, 16, 64));
            mx = fmaxf(mx, __shfl_xor(mx, 32, 64));

            float mn = fmaxf(m_run, mx);
            float al = __expf(m_run - mn);
            float ps = 0.f;
            #pragma unroll
            for (int n = 0; n < 4; ++n) {      // P -> per-wave LDS (4 bf16 / write)
                float p0 = __expf(ss[n][0] - mn);
                float p1 = __expf(ss[n][1] - mn);
                float p2 = __expf(ss[n][2] - mn);
                float p3 = __expf(ss[n][3] - mn);
                ps += (p0 + p1) + (p2 + p3);
                uint2 pw;
                pw.x = (uint)f2bf(p0) | ((uint)f2bf(p1) << 16);
                pw.y = (uint)f2bf(p2) | ((uint)f2bf(p3) << 16);
                *(uint2*)(Pw + l15*128 + ((n*32 + l4*8) ^ pswz)) = pw;
            }
            ps += __shfl_xor(ps, 16, 64);
            ps += __shfl_xor(ps, 32, 64);
            l_run = l_run*al + ps;
            m_run = mn;
            #pragma unroll
            for (int df = 0; df < 8; ++df) {
                of[df][0] *= al; of[df][1] *= al; of[df][2] *= al; of[df][3] *= al;
            }

            asm volatile("s_waitcnt lgkmcnt(0)" ::: "memory");  // P writes landed (wave-local)

            // ---- O^T += V P^T : lane owns q=l15, d = df*16 + l4*4 + reg ----
            #pragma unroll
            for (int ks = 0; ks < 2; ++ks) {
                short8 pa = *(const short8*)(Pw + l15*128 + ((ks*64 + l4*16) ^ pswz));
                #pragma unroll
                for (int df = 0; df < 8; ++df) {
                    int row = df*16 + l15;     // d row in frag
                    short8 vf = *(const short8*)((char*)Vts + row*128 + ((ks*64 + l4*16) ^ ((row&7)<<4)));
                    of[df] = __builtin_amdgcn_mfma_f32_16x16x32_bf16(vf, pa, of[df], 0, 0, 0);
                }
            }

            __syncthreads();                   // all waves done reading Ks/Vts
            if (more) {                        // T14: late LDS write
                #pragma unroll
                for (int l = 0; l < 4; ++l) {
                    int idx = l*256 + tid;
                    int rk = idx >> 4, ck = idx & 15;
                    *(uint4*)((char*)Ks + rk*256 + ((ck*16) ^ ((rk&7)<<4))) = pk[l];
                    int rv = idx >> 3, cv = idx & 7;
                    *(uint4*)((char*)Vts + rv*128 + ((cv*16) ^ ((rv&7)<<4))) = pv[l];
                }
            }
            __syncthreads();
        }

        // ---- epilogue: O/l -> att_bf (B,T,D_MODEL), 8B stores ----
        float inv = 1.f / l_run;
        size_t obase = ((size_t)(b*T_SEQ + qt*64 + w*16 + l15))*D_MODEL + h*HDIM;
        #pragma unroll
        for (int df = 0; df < 8; ++df) {
            uint2 w2;
            w2.x = (uint)f2bf(of[df][0]*inv) | ((uint)f2bf(of[df][1]*inv) << 16);
            w2.y = (uint)f2bf(of[df][2]*inv) | ((uint)f2bf(of[df][3]*inv) << 16);
            *(uint2*)&att_bf[obase + df*16 + l4*4] = w2;
        }
    }
}

// ---------------------------------------------------------------------------
extern "C" void kernel_launch(void* const* d_in, const int* in_sizes, int n_in,
                              void* d_out, int out_size, void* d_ws, size_t ws_size,
                              hipStream_t stream)
{
    const float* x     = (const float*)d_in[0];
    const float* w_qkv = (const float*)d_in[1];
    const float* b_qkv = (const float*)d_in[2];
    const float* w_out = (const float*)d_in[3];
    const float* b_out = (const float*)d_in[4];
    const float* psin  = (const float*)d_in[5];
    const float* pcos  = (const float*)d_in[6];
    float* out = (float*)d_out;

    const size_t per = (size_t)BATCH * NHEADS * T_SEQ * HDIM;  // 8,388,608
    float* Qb = (float*)d_ws;
    float* Kb = Qb + per;
    float* Vb = Kb + per;
    ushort* x_bf    = (ushort*)(Vb + per);
    ushort* wqkv_bf = x_bf + (size_t)MROWS*D_MODEL;
    ushort* wout_bf = wqkv_bf + (size_t)3*D_MODEL*D_MODEL;
    ushort* att_bf  = wout_bf + (size_t)D_MODEL*D_MODEL;
    ushort* Qbf     = att_bf + (size_t)MROWS*D_MODEL;
    ushort* Kbf     = Qbf + per;
    ushort* Vt      = Kbf + per;

    // 1) fp32 -> bf16 (RNE) for GEMM operands
    cvt_bf16<<<(MROWS*D_MODEL/4 + 255)/256, 256, 0, stream>>>(x, x_bf, MROWS*D_MODEL/4);
    cvt_bf16<<<(3*D_MODEL*D_MODEL/4 + 255)/256, 256, 0, stream>>>(w_qkv, wqkv_bf, 3*D_MODEL*D_MODEL/4);
    cvt_bf16<<<(D_MODEL*D_MODEL/4 + 255)/256, 256, 0, stream>>>(w_out, wout_bf, D_MODEL*D_MODEL/4);

    // 2) QKV projection (bf16 MFMA) + bias + clip, scatter fp32 (B,H,T,HDIM)
    gemm_bf16<0><<<dim3(3*D_MODEL/128, MROWS/128), 256, 0, stream>>>(
        x_bf, wqkv_bf, b_qkv, nullptr, Qb, Kb, Vb, MROWS, 3*D_MODEL, D_MODEL);

    // 3) RoPE -> bf16 Q/K ; V -> bf16 transposed (B,H,128,T)
    rope_bf16<<<(2u*BATCH*NHEADS*T_SEQ*64)/256, 256, 0, stream>>>(Qb, Kb, Qbf, Kbf, psin, pcos);
    vt_kernel<<<dim3(T_SEQ/32, BATCH*NHEADS), 256, 0, stream>>>(Vb, Vt);

    // 4) causal flash attention (bf16 MFMA, fp32 softmax), paired q-tiles
    attn_mfma<<<dim3(T_SEQ/128, NHEADS, BATCH), 256, 0, stream>>>(Qbf, Kbf, Vt, att_bf);

    // 5) output projection (bf16 MFMA) + bias
    gemm_bf16<1><<<dim3(D_MODEL/128, MROWS/128), 256, 0, stream>>>(
        att_bf, wout_bf, b_out, out, nullptr, nullptr, nullptr, MROWS, D_MODEL, D_MODEL);
}